// Round 24
// baseline (273.406 us; speedup 1.0000x reference)
//
#include <hip/hip_runtime.h>
#include <cstddef>

typedef unsigned short u16;

// Problem constants
constexpr int DM   = 512;    // d_model
constexpr int DN   = 64;     // d_state
constexpr int SEQL = 4096;
constexpr int CH   = 128;            // chunks per sequence for parallel scan
constexpr int LCH  = SEQL / CH;      // 32 steps per chunk
constexpr int KC   = DM + DN;        // 576: fused K for [Ys|u] @ Wcat

typedef __attribute__((ext_vector_type(8))) short bf16x8;
typedef __attribute__((ext_vector_type(4))) float f32x4;

__device__ inline u16 f2bf(float f) {
    unsigned int u = __float_as_uint(f);
    unsigned int r = u + 0x7FFFu + ((u >> 16) & 1u);   // round-to-nearest-even
    return (u16)(r >> 16);
}
__device__ inline float bf2f(u16 h) {
    return __uint_as_float(((unsigned int)h) << 16);
}

__device__ inline void gload_lds16(const void* g, void* l) {
    __builtin_amdgcn_global_load_lds(
        (const __attribute__((address_space(1))) void*)g,
        (__attribute__((address_space(3))) void*)l, 16, 0, 0);
}

// ---------------------------------------------------------------------------
// LayerNorm -> bf16: one wave per row of 512, writes Xn bf16.
// ---------------------------------------------------------------------------
__global__ __launch_bounds__(256) void k_ln(const float* __restrict__ X,
                                            const float* __restrict__ gamma,
                                            const float* __restrict__ beta,
                                            u16* __restrict__ Xn) {
    const int lane = threadIdx.x & 63;
    const int w    = threadIdx.x >> 6;
    const size_t row = (size_t)blockIdx.x * 4 + w;
    const float* xr = X + row * DM;
    float4 v0 = *reinterpret_cast<const float4*>(&xr[lane * 8]);
    float4 v1 = *reinterpret_cast<const float4*>(&xr[lane * 8 + 4]);
    float s  = v0.x + v0.y + v0.z + v0.w + v1.x + v1.y + v1.z + v1.w;
    float s2 = v0.x*v0.x + v0.y*v0.y + v0.z*v0.z + v0.w*v0.w
             + v1.x*v1.x + v1.y*v1.y + v1.z*v1.z + v1.w*v1.w;
#pragma unroll
    for (int o = 32; o > 0; o >>= 1) {
        s  += __shfl_xor(s, o);
        s2 += __shfl_xor(s2, o);
    }
    const float mu = s * (1.0f / DM);
    const float rs = rsqrtf(s2 * (1.0f / DM) - mu * mu + 1e-3f);
    float4 g0 = *reinterpret_cast<const float4*>(&gamma[lane * 8]);
    float4 g1 = *reinterpret_cast<const float4*>(&gamma[lane * 8 + 4]);
    float4 b0 = *reinterpret_cast<const float4*>(&beta[lane * 8]);
    float4 b1 = *reinterpret_cast<const float4*>(&beta[lane * 8 + 4]);
    union { u16 h[8]; uint4 v; } pk;
    pk.h[0] = f2bf((v0.x - mu) * rs * g0.x + b0.x);
    pk.h[1] = f2bf((v0.y - mu) * rs * g0.y + b0.y);
    pk.h[2] = f2bf((v0.z - mu) * rs * g0.z + b0.z);
    pk.h[3] = f2bf((v0.w - mu) * rs * g0.w + b0.w);
    pk.h[4] = f2bf((v1.x - mu) * rs * g1.x + b1.x);
    pk.h[5] = f2bf((v1.y - mu) * rs * g1.y + b1.y);
    pk.h[6] = f2bf((v1.z - mu) * rs * g1.z + b1.z);
    pk.h[7] = f2bf((v1.w - mu) * rs * g1.w + b1.w);
    *reinterpret_cast<uint4*>(&Xn[row * DM + lane * 8]) = pk.v;
}

// ---------------------------------------------------------------------------
// Transpose+convert (+optional per-k scale): Wt[n*ldo + k] = bf16(s[k]*W[k*N+n])
// grid (N/64, K/64).
// ---------------------------------------------------------------------------
__global__ __launch_bounds__(256) void k_wtransS(const float* __restrict__ W,
                                                 u16* __restrict__ Wt,
                                                 int K, int N, int ldo,
                                                 const float* __restrict__ scale) {
    __shared__ float tile[64][65];
    const int bx = blockIdx.x, by = blockIdx.y;
    const int tx = threadIdx.x & 63, ty = threadIdx.x >> 6;
#pragma unroll
    for (int r = ty; r < 64; r += 4)
        tile[r][tx] = W[(size_t)(by * 64 + r) * N + bx * 64 + tx];
    __syncthreads();
    const float sc = scale ? scale[by * 64 + tx] : 1.0f;
#pragma unroll
    for (int r = ty; r < 64; r += 4)
        Wt[(size_t)(bx * 64 + r) * ldo + by * 64 + tx] = f2bf(sc * tile[tx][r]);
}

// ---------------------------------------------------------------------------
// Wc = W_s2o @ W_out (64x512, K=512), written transposed into Wcat[n*576 + k].
// ---------------------------------------------------------------------------
__global__ __launch_bounds__(256) void k_wcat(const float* __restrict__ Ws2o,
                                              const float* __restrict__ Wout,
                                              u16* __restrict__ Wcat) {
    const int tn = threadIdx.x & 63;
    const int tk = threadIdx.x >> 6;
    const int n  = blockIdx.x * 64 + tn;
    const int k  = blockIdx.y * 4 + tk;
    float s = 0.f;
#pragma unroll 8
    for (int j = 0; j < DM; ++j)
        s = fmaf(Ws2o[(size_t)k * DM + j], Wout[(size_t)j * DM + n], s);
    Wcat[(size_t)n * KC + k] = f2bf(s);
}

// ---------------------------------------------------------------------------
// GEMM1: Ub = bf16(Xn @ WinT^T + b_in). 128x128 tile, BK=32, 2-phase dbuf,
// XCD swizzle. grid (4, M/128).
// ---------------------------------------------------------------------------
__global__ __launch_bounds__(256) void k_g1(const u16* __restrict__ A,
                                            const u16* __restrict__ Bt,
                                            const float* __restrict__ bias,
                                            u16* __restrict__ Out)
{
    __shared__ u16 As[2][4096];
    __shared__ u16 Bs[2][4096];
    const int tid = threadIdx.x, lane = tid & 63, w = tid >> 6;
    const int wr = w >> 1, wc = w & 1;
    int lid = blockIdx.y * gridDim.x + blockIdx.x;
    const int cpx = (gridDim.x * gridDim.y) >> 3;
    lid = (lid & 7) * cpx + (lid >> 3);            // bijective XCD swizzle
    const int n0 = (lid & 3) * 128;
    const int m0 = (lid >> 2) * 128;

    const int srow = tid >> 2, sk = (tid & 3) * 8;
    const u16* aR = A  + (size_t)(m0 + srow) * DM + sk;
    const u16* bR = Bt + (size_t)(n0 + srow) * DM + sk;
    const int kg = lane >> 4, lr = lane & 15;
    const int aoff = (wr * 64 + lr) * 32 + kg * 8;
    const int boff = (wc * 64 + lr) * 32 + kg * 8;

    f32x4 acc[4][4];
#pragma unroll
    for (int i = 0; i < 4; i++)
#pragma unroll
      for (int j = 0; j < 4; j++) acc[i][j] = (f32x4){0.f, 0.f, 0.f, 0.f};

    auto STAGE = [&](int buf, int s) {
        const u16* a0 = aR + s * 32;
        const u16* b0 = bR + s * 32;
        gload_lds16(a0,           &As[buf][w * 512]);
        gload_lds16(a0 + 64 * DM, &As[buf][2048 + w * 512]);
        gload_lds16(b0,           &Bs[buf][w * 512]);
        gload_lds16(b0 + 64 * DM, &Bs[buf][2048 + w * 512]);
    };

    STAGE(0, 0);
    __syncthreads();
    for (int s = 0; s < 16; ++s) {
        const int cur = s & 1;
        if (s + 1 < 16) STAGE(cur ^ 1, s + 1);
        bf16x8 af[4], bfr[4];
#pragma unroll
        for (int i = 0; i < 4; i++)
            af[i]  = *reinterpret_cast<const bf16x8*>(&As[cur][aoff + i * 512]);
#pragma unroll
        for (int j = 0; j < 4; j++)
            bfr[j] = *reinterpret_cast<const bf16x8*>(&Bs[cur][boff + j * 512]);
#pragma unroll
        for (int i = 0; i < 4; i++)
#pragma unroll
          for (int j = 0; j < 4; j++)
            acc[i][j] = __builtin_amdgcn_mfma_f32_16x16x32_bf16(af[i], bfr[j], acc[i][j], 0, 0, 0);
        __syncthreads();
    }

#pragma unroll
    for (int j = 0; j < 4; j++) {
        const int col = n0 + wc * 64 + j * 16 + lr;
        const float bv = bias[col];
#pragma unroll
        for (int i = 0; i < 4; i++) {
            const int rbase = m0 + wr * 64 + i * 16 + kg * 4;
#pragma unroll
            for (int r = 0; r < 4; r++)
                Out[(size_t)(rbase + r) * DM + col] = f2bf(acc[i][j][r] + bv);
        }
    }
}

// ---------------------------------------------------------------------------
// GEMM2: [xs|Bm|Cm] = Ub @ WbcxT^T (192x512). BM=64 tile, 2-phase dbuf.
// ---------------------------------------------------------------------------
__global__ __launch_bounds__(256) void k_mfma_bcx(
    const u16* __restrict__ A, const u16* __restrict__ Bt,
    const float* __restrict__ bB, const float* __restrict__ bC,
    float* __restrict__ Bu, float* __restrict__ Cc)
{
    __shared__ u16 As[2][2048];
    __shared__ u16 Bs[2][6144];
    const int tid = threadIdx.x, lane = tid & 63, w = tid >> 6;
    const int m0 = blockIdx.x * 64;

    f32x4 acc[12];
#pragma unroll
    for (int j = 0; j < 12; j++) acc[j] = (f32x4){0.f, 0.f, 0.f, 0.f};

    const int srow = tid >> 2, sk = (tid & 3) * 8;
    const u16* aR = A  + (size_t)(m0 + srow) * DM + sk;
    const u16* bR = Bt + (size_t)srow * DM + sk;
    const int kg = lane >> 4, lr = lane & 15;
    const int aoff = (w * 16 + lr) * 32 + kg * 8;

    auto STAGE = [&](int buf, int s) {
        const u16* a0 = aR + s * 32;
        const u16* b0 = bR + s * 32;
        gload_lds16(a0,            &As[buf][w * 512]);
        gload_lds16(b0,            &Bs[buf][w * 512]);
        gload_lds16(b0 + 64 * DM,  &Bs[buf][2048 + w * 512]);
        gload_lds16(b0 + 128 * DM, &Bs[buf][4096 + w * 512]);
    };

    STAGE(0, 0);
    __syncthreads();
    for (int s = 0; s < 16; ++s) {
        const int cur = s & 1;
        if (s + 1 < 16) STAGE(cur ^ 1, s + 1);
        bf16x8 af = *reinterpret_cast<const bf16x8*>(&As[cur][aoff]);
#pragma unroll
        for (int j = 0; j < 12; j++) {
            bf16x8 bfr = *reinterpret_cast<const bf16x8*>(&Bs[cur][(j * 16 + lr) * 32 + kg * 8]);
            acc[j] = __builtin_amdgcn_mfma_f32_16x16x32_bf16(af, bfr, acc[j], 0, 0, 0);
        }
        __syncthreads();
    }

#pragma unroll
    for (int j = 0; j < 4; j++) {
        const int col = j * 16 + lr;
        const float bBv = bB[col], bCv = bC[col];
#pragma unroll
        for (int r = 0; r < 4; r++) {
            const int grow = m0 + w * 16 + kg * 4 + r;
            const float xs = acc[j][r];
            const float bm = acc[j + 4][r] + bBv;
            const float cm = acc[j + 8][r] + bCv;
            Bu[(size_t)grow * DN + col] = bm * xs;
            Cc[(size_t)grow * DN + col] = cm;
        }
    }
}

// ---------------------------------------------------------------------------
// Chunked parallel scan (exact): h[t] = a*h[t-1] + Bu[t], a const per channel.
// ---------------------------------------------------------------------------
__global__ void k_scan1(const float* __restrict__ Bu, const float* __restrict__ Alog,
                        float* __restrict__ Hl) {
    const int n = threadIdx.x;
    const int c = blockIdx.x;
    const int b = blockIdx.y;
    const float a = expf(-expf(Alog[n]));
    const float* p = Bu + ((size_t)(b * SEQL + c * LCH)) * DN + n;
    float h = 0.f;
#pragma unroll
    for (int t = 0; t < LCH; t++) h = fmaf(a, h, p[(size_t)t * DN]);
    Hl[(b * DN + n) * CH + c] = h;
}

__global__ void k_carry(const float* __restrict__ Hl, const float* __restrict__ Alog,
                        float* __restrict__ Hin) {
    const int i = threadIdx.x;        // b*64 + n
    const int n = i & 63;
    const float a  = expf(-expf(Alog[n]));
    const float aL = powf(a, (float)LCH);
    float hend = 0.f;
    for (int c = 0; c < CH; c++) {
        Hin[(size_t)i * CH + c] = hend;
        hend = fmaf(aL, hend, Hl[(size_t)i * CH + c]);
    }
}

__global__ void k_scan2(const float* __restrict__ Bu, const float* __restrict__ Cc,
                        const float* __restrict__ Hin, const float* __restrict__ Alog,
                        u16* __restrict__ Ysb) {
    const int n = threadIdx.x;
    const int c = blockIdx.x;
    const int b = blockIdx.y;
    const float a = expf(-expf(Alog[n]));
    float h = Hin[((size_t)(b * DN + n)) * CH + c];
    const size_t base = ((size_t)(b * SEQL + c * LCH)) * DN + n;
#pragma unroll
    for (int t = 0; t < LCH; t++) {
        h = fmaf(a, h, Bu[base + (size_t)t * DN]);
        Ysb[base + (size_t)t * DN] = f2bf(Cc[base + (size_t)t * DN] * h);
    }
}

// ---------------------------------------------------------------------------
// Fused GEMM3+4, B-resident streaming version (BN=32, 37KB LDS):
// out = [Ys | u] @ Wcat^T + b_out + X.  K = 576.
// B-panel (32x576 bf16 +8 pad = 37376B) loaded to LDS ONCE; main loop has NO
// barriers: A streams global->regs, B via padded ds_read_b128. 4 blocks/CU.
// grid 1024; bid%8 == stripe%8 so a stripe's 16 n-blocks share one XCD.
// ---------------------------------------------------------------------------
__global__ __launch_bounds__(256) void k_gfuse_stream(
    const u16* __restrict__ Ysb, const u16* __restrict__ Ub,
    const u16* __restrict__ Wcat, const float* __restrict__ bias,
    const float* __restrict__ X, float* __restrict__ Out)
{
    constexpr int LDB = 584;                 // 576 + 8 pad (u16)
    __shared__ u16 Bsh[32 * LDB];            // 37376 B
    const int tid = threadIdx.x, lane = tid & 63, w = tid >> 6;
    const int wr = w >> 1, wc = w & 1;       // block: 128 rows x 32 cols
    const int bid = blockIdx.x;
    const int t      = bid >> 3;
    const int nblk   = t & 15;
    const int stripe = (bid & 7) + 8 * (t >> 4);     // 0..63
    const int n0     = nblk * 32;

    // ---- B panel -> LDS (once) ----
    {
        const int col = tid & 31, q = tid >> 5;      // 32 cols x 8 chunk-lanes
        const u16* src = Wcat + (size_t)(n0 + col) * KC;
#pragma unroll
        for (int r = 0; r < 9; ++r) {
            const int chunk = q + r * 8;             // 0..71 (16B chunks)
            const uint4 v = *reinterpret_cast<const uint4*>(src + chunk * 8);
            *reinterpret_cast<uint4*>(&Bsh[col * LDB + chunk * 8]) = v;
        }
    }
    __syncthreads();

    const int kg = lane >> 4, lr = lane & 15;
    const int bbase = (wc * 16 + lr) * LDB + kg * 8;

    for (int mt = 0; mt < 4; ++mt) {
        const int m0 = stripe * 512 + mt * 128;
        f32x4 acc[4];
#pragma unroll
        for (int i = 0; i < 4; i++) acc[i] = (f32x4){0.f, 0.f, 0.f, 0.f};

        const u16* aY0 = Ysb + (size_t)(m0 + wr * 64 + lr) * DN + kg * 8;
        const u16* aU0 = Ub  + (size_t)(m0 + wr * 64 + lr) * DM + kg * 8;

#pragma unroll
        for (int ks = 0; ks < 18; ++ks) {
            bf16x8 af[4];
#pragma unroll
            for (int i = 0; i < 4; ++i) {
                if (ks < 2)
                    af[i] = *reinterpret_cast<const bf16x8*>(aY0 + (size_t)(i * 16) * DN + ks * 32);
                else
                    af[i] = *reinterpret_cast<const bf16x8*>(aU0 + (size_t)(i * 16) * DM + (ks - 2) * 32);
            }
            const bf16x8 bf0 = *reinterpret_cast<const bf16x8*>(&Bsh[bbase + ks * 32]);
#pragma unroll
            for (int i = 0; i < 4; ++i)
                acc[i] = __builtin_amdgcn_mfma_f32_16x16x32_bf16(af[i], bf0, acc[i], 0, 0, 0);
        }

        const int col = n0 + wc * 16 + lr;
        const float bv = bias[col];
#pragma unroll
        for (int i = 0; i < 4; ++i) {
            const int rbase = m0 + wr * 64 + i * 16 + kg * 4;
#pragma unroll
            for (int r = 0; r < 4; ++r) {
                const size_t idx = (size_t)(rbase + r) * DM + col;
                Out[idx] = acc[i][r] + bv + X[idx];
            }
        }
    }
}

// ---------------------------------------------------------------------------
extern "C" void kernel_launch(void* const* d_in, const int* in_sizes, int n_in,
                              void* d_out, int out_size, void* d_ws, size_t ws_size,
                              hipStream_t stream) {
    const float* X     = (const float*)d_in[0];
    const float* gamma = (const float*)d_in[1];
    const float* beta  = (const float*)d_in[2];
    const float* W_in  = (const float*)d_in[3];
    const float* b_in  = (const float*)d_in[4];
    const float* W_xs  = (const float*)d_in[5];
    const float* W_B   = (const float*)d_in[6];
    const float* b_B   = (const float*)d_in[7];
    const float* W_C   = (const float*)d_in[8];
    const float* b_C   = (const float*)d_in[9];
    const float* A_log = (const float*)d_in[10];
    const float* Dv    = (const float*)d_in[11];
    const float* W_s2o = (const float*)d_in[12];
    const float* W_out = (const float*)d_in[13];
    const float* b_out = (const float*)d_in[14];
    float* out = (float*)d_out;

    const int M = in_sizes[0] / DM;     // 32768 rows (B*S)
    const int B = M / SEQL;             // 8

    // Workspace layout (~90 MB)
    float* ws  = (float*)d_ws;
    float* Bu  = ws;                                // M*DN f32
    float* Cc  = Bu + (size_t)M * DN;               // M*DN f32
    float* Hl  = Cc + (size_t)M * DN;               // B*DN*CH
    float* Hin = Hl + (size_t)B * DN * CH;          // B*DN*CH
    u16* Xn    = (u16*)(Hin + (size_t)B * DN * CH); // M*DM bf16
    u16* Ub    = Xn + (size_t)M * DM;               // M*DM bf16
    u16* Ysb   = Ub + (size_t)M * DM;               // M*DN bf16
    u16* WinT  = Ysb + (size_t)M * DN;              // 512*512
    u16* WbcxT = WinT + (size_t)DM * DM;            // 192*512
    u16* WcatT = WbcxT + (size_t)3 * DN * DM;       // 512*576

    k_ln<<<M / 4, 256, 0, stream>>>(X, gamma, beta, Xn);
    k_wtransS<<<dim3(8, 8), 256, 0, stream>>>(W_in, WinT, DM, DM, DM, nullptr);
    k_wtransS<<<dim3(1, 8), 256, 0, stream>>>(W_xs, WbcxT,            DM, DN, DM, nullptr);
    k_wtransS<<<dim3(1, 8), 256, 0, stream>>>(W_B,  WbcxT + 64 * DM,  DM, DN, DM, nullptr);
    k_wtransS<<<dim3(1, 8), 256, 0, stream>>>(W_C,  WbcxT + 128 * DM, DM, DN, DM, nullptr);
    k_wtransS<<<dim3(8, 8), 256, 0, stream>>>(W_out, WcatT + 64, DM, DM, KC, Dv);
    k_wcat<<<dim3(8, 16), 256, 0, stream>>>(W_s2o, W_out, WcatT);

    k_g1<<<dim3(4, M / 128), 256, 0, stream>>>(Xn, WinT, b_in, Ub);
    k_mfma_bcx<<<dim3(M / 64), 256, 0, stream>>>(Ub, WbcxT, b_B, b_C, Bu, Cc);
    k_scan1<<<dim3(CH, B), 64, 0, stream>>>(Bu, A_log, Hl);
    k_carry<<<1, B * DN, 0, stream>>>(Hl, A_log, Hin);
    k_scan2<<<dim3(CH, B), 64, 0, stream>>>(Bu, Cc, Hin, A_log, Ysb);
    k_gfuse_stream<<<1024, 256, 0, stream>>>(Ysb, Ub, WcatT, b_out, X, out);
}